// Round 11
// baseline (803.551 us; speedup 1.0000x reference)
//
#include <hip/hip_runtime.h>
#include <hip/hip_bf16.h>
#include <stdint.h>

#define B_ 16
#define T_ 30
#define H_ 64
#define W_ 44
#define HW_ (H_*W_)            // 2816
#define THW_ (T_*HW_)          // 84480

// padded transposed layout: xt[b][half][t:30][hp:66][wp:46][32 ic] bf16
#define HP_ 66
#define WP_ 46
#define PPLANE_ (HP_*WP_)      // 3036
#define PPOS_ (T_*PPLANE_)     // 91080 pos per (b,half)

// conv tiling: 256 thr (4 waves), out tile 2t x 8h x 16w = 256 pos, 64 oc
#define SZ2 4
#define SY2 10
#define SX2 18
#define NS2 (SZ2*SY2*SX2)      // 720 staged spatial rows (64 B each per K-half)

// LDS 16B-chunk swizzle (validated R3/R10: SQ_LDS_BANK_CONFLICT = 0)
#define SWZ(v) (((v) >> 1) & 3)

typedef __bf16 bf16x8 __attribute__((ext_vector_type(8)));
typedef float f32x4 __attribute__((ext_vector_type(4)));

static __device__ __forceinline__ short f2bf(float f) {
    __hip_bfloat16 h = __float2bfloat16(f);
    union { __hip_bfloat16 b; short s; } u; u.b = h; return u.s;
}

static __device__ __forceinline__ void gload_lds16(const short* g, short* l) {
    __builtin_amdgcn_global_load_lds((const __attribute__((address_space(1))) void*)g,
                                     (__attribute__((address_space(3))) void*)l, 16, 0, 0);
}

// ---------------- kernel 0: transpose + fused GAP ----------------
__global__ __launch_bounds__(256) void transpose_kernel(const float* __restrict__ x,
                                                        short* __restrict__ xt,
                                                        float* __restrict__ gap) {
    __shared__ short lb[64*52];
    __shared__ float gsum[64];
    int blk = blockIdx.x;
    int b = blk / (T_*HP_);
    int r = blk - b*(T_*HP_);
    int t = r / HP_;
    int hp = r - t*HP_;
    int tid = threadIdx.x;
    bool interior = (hp >= 1) && (hp <= H_);
    float rsum = 0.f;
    {
        int ic = tid >> 2, g = tid & 3;
        if (interior) {
            int h = hp - 1;
            const float4* row = (const float4*)(x + ((size_t)(b*64 + ic)*T_ + t)*HW_ + h*W_);
            #pragma unroll
            for (int q = g; q < 11; q += 4) {
                float4 v = row[q];
                short4 s4;
                s4.x = f2bf(v.x); s4.y = f2bf(v.y); s4.z = f2bf(v.z); s4.w = f2bf(v.w);
                *(short4*)&lb[ic*52 + q*4] = s4;
                rsum += (v.x + v.y) + (v.z + v.w);
            }
        }
        rsum += __shfl_xor(rsum, 1);
        rsum += __shfl_xor(rsum, 2);
        if ((tid & 3) == 0) gsum[ic] = rsum;
    }
    __syncthreads();
    if (interior && tid < 64)
        atomicAdd(&gap[b*64 + tid], gsum[tid] * (1.0f / THW_));
    for (int e = tid; e < WP_*16; e += 256) {
        int wp = e >> 4, i4 = (e & 15) * 4;
        short4 s4 = make_short4(0,0,0,0);
        if (interior && wp >= 1 && wp <= W_) {
            int w = wp - 1;
            s4.x = lb[(i4+0)*52 + w];
            s4.y = lb[(i4+1)*52 + w];
            s4.z = lb[(i4+2)*52 + w];
            s4.w = lb[(i4+3)*52 + w];
        }
        size_t pos = (size_t)t*PPLANE_ + hp*WP_ + wp;
        short* dst = xt + ((size_t)(b*2 + (i4 >> 5))*PPOS_ + pos)*32 + (i4 & 31);
        *(short4*)dst = s4;
    }
}

// ---------------- kernel 2: reduce FC + fc1 + sigmoid ----------------
__global__ __launch_bounds__(256) void fc_kernel(const float* __restrict__ gap,
        const float* __restrict__ w_reduce, const float* __restrict__ b_reduce,
        const float* __restrict__ w_fc1, const float* __restrict__ b_fc1,
        float* __restrict__ h_out) {
    __shared__ float gl[256];
    int t = threadIdx.x;
    {
        int b = t >> 4, j = t & 15;
        float a = b_reduce[j];
        #pragma unroll
        for (int c = 0; c < 64; ++c) a += gap[b*64 + c] * w_reduce[j*64 + c];
        gl[b*16 + j] = a;
    }
    __syncthreads();
    for (int idx = t; idx < 2048; idx += 256) {
        int b = idx >> 7, j = idx & 127;
        float v = b_fc1[j];
        #pragma unroll
        for (int i = 0; i < 16; ++i) v += gl[b*16 + i] * w_fc1[j*16 + i];
        h_out[idx] = 1.0f / (1.0f + expf(-v));
    }
}

// ---------------- kernel 3: dynamic weights bf16 (+ zero block) ----------------
__global__ __launch_bounds__(256) void wdyn_kernel(const float* __restrict__ w_fc2,
        const float* __restrict__ h, short* __restrict__ wdyn, short* __restrict__ zblk) {
    if (blockIdx.x == 0 && threadIdx.x < 128) zblk[threadIdx.x] = 0;
    int b = blockIdx.x / 27, tap = blockIdx.x % 27;
    short* dst = wdyn + ((size_t)b*27 + tap) * 4096;
    for (int e = threadIdx.x; e < 4096; e += 256) {
        int oc = e >> 6, ic = e & 63;
        float wv = w_fc2[(oc*64 + ic)*27 + tap];
        float hv = h[b*128 + 2*oc + (ic >> 5)];
        dst[e] = f2bf(wv * hv);
    }
}

#define DO_STEP(tap, r0, r1, r2, r3) do {                              \
    int _kd = (tap)/9, _rr = (tap)-_kd*9, _kh = _rr/3, _kw = _rr-_kh*3;\
    int _sb = (tzw + _kd)*180 + (hw4 + _kh)*18 + _kw + ln;             \
    __builtin_amdgcn_s_setprio(1);                                     \
    _Pragma("unroll")                                                  \
    for (int _j = 0; _j < 4; ++_j) {                                   \
        int _s = _sb + _j*18;                                          \
        bf16x8 _bv = *(const bf16x8*)&xs[_s*32 + ((kg ^ SWZ(_s)) * 8)];\
        acc[0][_j] = __builtin_amdgcn_mfma_f32_16x16x32_bf16(r0, _bv, acc[0][_j], 0, 0, 0); \
        acc[1][_j] = __builtin_amdgcn_mfma_f32_16x16x32_bf16(r1, _bv, acc[1][_j], 0, 0, 0); \
        acc[2][_j] = __builtin_amdgcn_mfma_f32_16x16x32_bf16(r2, _bv, acc[2][_j], 0, 0, 0); \
        acc[3][_j] = __builtin_amdgcn_mfma_f32_16x16x32_bf16(r3, _bv, acc[3][_j], 0, 0, 0); \
    }                                                                  \
    __builtin_amdgcn_s_setprio(0);                                     \
} while (0)

// One K-step: publish next step's weights (bank (g+1)&1), prefetch step g+2,
// consume bank g&1. Compile-time g -> all addressing folds to immediates.
#define FULLSTEP(g) do {                                               \
    if ((g) < 53) {                                                    \
        *(uint4*)(wbb + ((((g)+1)&1) ? 2048 : 0) + woff) = wr;         \
        if ((g) <= 51) wr = wload((g)+2);                              \
    }                                                                  \
    bf16x8 a0, a1, a2, a3;                                             \
    {                                                                  \
        const short* _wq = wbb + (((g)&1) ? 2048 : 0);                 \
        int _cw = (kg ^ SWZ(ln)) * 8;                                  \
        a0 = *(const bf16x8*)&_wq[(ln     )*32 + _cw];                 \
        a1 = *(const bf16x8*)&_wq[(ln + 16)*32 + _cw];                 \
        a2 = *(const bf16x8*)&_wq[(ln + 32)*32 + _cw];                 \
        a3 = *(const bf16x8*)&_wq[(ln + 48)*32 + _cw];                 \
    }                                                                  \
    DO_STEP((g) - (((g) >= 27) ? 27 : 0), a0, a1, a2, a3);             \
} while (0)

#define STEP_SYNC() do {                                               \
    asm volatile("s_waitcnt lgkmcnt(0)" ::: "memory");                 \
    __builtin_amdgcn_s_barrier();                                      \
} while (0)

// ---------------- kernel 4: implicit-GEMM dynamic conv3d ----------------
// R10 tiling at 3 blocks/CU, but: wb double-buffered (8KB), ONE raw barrier
// per step with lgkmcnt-only wait (never drain vmcnt in-loop -> weight
// prefetch stays in flight across barriers, T3/T4). LDS 54,272B x3 = 162,816
// <= 163,840. Fully unrolled steps: compile-time tap addressing.
__global__ __launch_bounds__(256, 3) void conv_kernel(const short* __restrict__ xt,
        const short* __restrict__ wdyn, const short* __restrict__ zblk,
        float* __restrict__ out) {
    __shared__ short xs[NS2*32];     // 46,080 B
    __shared__ short wb[2][2048];    //  8,192 B double-buffered tap weights

    // XCD swizzle: 5760 blocks = 8 XCDs x 720 contiguous (5760 % 8 == 0)
    int bid = (blockIdx.x & 7) * 720 + (blockIdx.x >> 3);
    int b = bid / 360; int r = bid - b*360;
    int tzt = r / 24; r -= tzt*24;
    int tyt = r / 3;  int txt = r - tyt*3;
    int t0 = tzt*2, h0 = tyt*8, w0 = txt*16;

    int tid = threadIdx.x, wid = tid >> 6, lane = tid & 63;
    int ln = lane & 15, kg = lane >> 4;
    int l4 = lane >> 2, c = lane & 3;
    int tzw = wid & 1, hw4 = (wid >> 1) * 4;
    int woc = tid >> 2, wseg = tid & 3;          // weight staging role
    int woff = woc*32 + ((wseg ^ SWZ(woc)) * 8); // swizzled wb slot (shorts)
    short* wbb = &wb[0][0];

    const short* wdb = wdyn + (size_t)b * 27 * 4096;

    f32x4 acc[4][4];
    #pragma unroll
    for (int mt = 0; mt < 4; ++mt)
        #pragma unroll
        for (int j = 0; j < 4; ++j) acc[mt][j] = f32x4{0.f, 0.f, 0.f, 0.f};

    auto wload = [&](int gn) {                   // weights for step gn (16B/thr)
        int tap = gn - ((gn >= 27) ? 27 : 0);
        int nh  = (gn >= 27) ? 32 : 0;
        return *(const uint4*)(wdb + tap*4096 + nh + woc*64 + wseg*8);
    };
    auto stage_x = [&](int half) {               // 45 gload_lds over 4 waves
        const short* xbh = xt + (size_t)(b*2 + half) * PPOS_ * 32;
        #pragma unroll
        for (int ii = 0; ii < 12; ++ii) {
            int inst = ii*4 + wid;
            if (inst < 45) {
                int s = inst*16 + l4;
                int z = s / 180; int rr = s - z*180;
                int y = rr / 18; int xx = rr - y*18;
                int t = t0 + z - 1;
                int seg = (c ^ SWZ(s)) * 8;
                const short* src = ((unsigned)t < (unsigned)T_)
                    ? xbh + ((size_t)t*PPLANE_ + (h0+y)*WP_ + (w0+xx))*32 + seg
                    : zblk + seg;
                gload_lds16(src, xs + inst*512);
            }
        }
    };

    // prologue: xs half 0 + bank0 = W(0); W(1) left in flight across barrier
    stage_x(0);
    uint4 wr = wload(0);
    asm volatile("s_waitcnt vmcnt(0)" ::: "memory");   // own xs loads + wr done
    *(uint4*)(wbb + woff) = wr;
    wr = wload(1);
    STEP_SYNC();                                 // all xs(0)+bank0 visible

    #pragma unroll
    for (int g = 0; g < 54; ++g) {
        FULLSTEP(g);
        if (g == 26) {                           // half transition
            STEP_SYNC();                         // xs(0) reads complete
            stage_x(1);
            asm volatile("s_waitcnt vmcnt(0)" ::: "memory");
            __builtin_amdgcn_s_barrier();        // xs(1) landed everywhere
        } else if (g < 53) {
            STEP_SYNC();                         // single barrier per step
        }
    }

    // epilogue: D layout col=lane&15 (pos=w), row=(lane>>4)*4+ri (oc)
    int t = t0 + tzw;
    int wv = w0 + ln;
    if (wv < W_) {
        #pragma unroll
        for (int mt = 0; mt < 4; ++mt) {
            size_t obase = ((size_t)(b*64 + mt*16 + kg*4) * T_ + t) * HW_;
            #pragma unroll
            for (int j = 0; j < 4; ++j) {
                float* o = out + obase + (h0 + hw4 + j)*W_ + wv;
                #pragma unroll
                for (int ri = 0; ri < 4; ++ri)
                    o[(size_t)ri * THW_] = acc[mt][j][ri];
            }
        }
    }
}

extern "C" void kernel_launch(void* const* d_in, const int* in_sizes, int n_in,
                              void* d_out, int out_size, void* d_ws, size_t ws_size,
                              hipStream_t stream) {
    const float* x        = (const float*)d_in[0];
    const float* w_reduce = (const float*)d_in[1];
    const float* b_reduce = (const float*)d_in[2];
    const float* w_fc1    = (const float*)d_in[3];
    const float* b_fc1    = (const float*)d_in[4];
    const float* w_fc2    = (const float*)d_in[5];
    float* out = (float*)d_out;

    // ws layout: gap 4KB | h 8KB | wdyn 3.375MB | zblk 256B | xt 186.5MB (+slack)
    float* gap  = (float*)d_ws;
    float* h    = gap + 1024;
    short* wdyn = (short*)(h + 2048);
    short* zblk = wdyn + (size_t)B_*27*4096;
    short* xt   = zblk + 128;

    hipMemsetAsync(gap, 0, 1024*sizeof(float), stream);   // atomic accumulator
    transpose_kernel<<<B_*T_*HP_, 256, 0, stream>>>(x, xt, gap);
    fc_kernel       <<<1,         256, 0, stream>>>(gap, w_reduce, b_reduce, w_fc1, b_fc1, h);
    wdyn_kernel     <<<B_*27,     256, 0, stream>>>(w_fc2, h, wdyn, zblk);
    conv_kernel     <<<B_*360,    256, 0, stream>>>(xt, wdyn, zblk, out);
}

// Round 12
// 512.619 us; speedup vs baseline: 1.5675x; 1.5675x over previous
//
#include <hip/hip_runtime.h>
#include <hip/hip_bf16.h>
#include <stdint.h>

#define B_ 16
#define T_ 30
#define H_ 64
#define W_ 44
#define HW_ (H_*W_)            // 2816
#define THW_ (T_*HW_)          // 84480

// padded transposed layout: xt[b][half][t:30][hp:66][wp:46][32 ic] bf16
#define HP_ 66
#define WP_ 46
#define PPLANE_ (HP_*WP_)      // 3036
#define PPOS_ (T_*PPLANE_)     // 91080 pos per (b,half)

// conv tiling: 256 thr (4 waves), out tile 2t x 8h x 16w = 256 pos, 64 oc
#define SZ2 4
#define SY2 10
#define SX2 18
#define NS2 (SZ2*SY2*SX2)      // 720 staged spatial rows (64 B each per K-half)

// LDS 16B-chunk swizzle (validated R3/R10: SQ_LDS_BANK_CONFLICT = 0)
#define SWZ(v) (((v) >> 1) & 3)

typedef __bf16 bf16x8 __attribute__((ext_vector_type(8)));
typedef float f32x4 __attribute__((ext_vector_type(4)));

static __device__ __forceinline__ short f2bf(float f) {
    __hip_bfloat16 h = __float2bfloat16(f);
    union { __hip_bfloat16 b; short s; } u; u.b = h; return u.s;
}

static __device__ __forceinline__ void gload_lds16(const short* g, short* l) {
    __builtin_amdgcn_global_load_lds((const __attribute__((address_space(1))) void*)g,
                                     (__attribute__((address_space(3))) void*)l, 16, 0, 0);
}

// ---------------- kernel 0: transpose + fused GAP ----------------
__global__ __launch_bounds__(256) void transpose_kernel(const float* __restrict__ x,
                                                        short* __restrict__ xt,
                                                        float* __restrict__ gap) {
    __shared__ short lb[64*52];
    __shared__ float gsum[64];
    int blk = blockIdx.x;
    int b = blk / (T_*HP_);
    int r = blk - b*(T_*HP_);
    int t = r / HP_;
    int hp = r - t*HP_;
    int tid = threadIdx.x;
    bool interior = (hp >= 1) && (hp <= H_);
    float rsum = 0.f;
    {
        int ic = tid >> 2, g = tid & 3;
        if (interior) {
            int h = hp - 1;
            const float4* row = (const float4*)(x + ((size_t)(b*64 + ic)*T_ + t)*HW_ + h*W_);
            #pragma unroll
            for (int q = g; q < 11; q += 4) {
                float4 v = row[q];
                short4 s4;
                s4.x = f2bf(v.x); s4.y = f2bf(v.y); s4.z = f2bf(v.z); s4.w = f2bf(v.w);
                *(short4*)&lb[ic*52 + q*4] = s4;
                rsum += (v.x + v.y) + (v.z + v.w);
            }
        }
        rsum += __shfl_xor(rsum, 1);
        rsum += __shfl_xor(rsum, 2);
        if ((tid & 3) == 0) gsum[ic] = rsum;
    }
    __syncthreads();
    if (interior && tid < 64)
        atomicAdd(&gap[b*64 + tid], gsum[tid] * (1.0f / THW_));
    for (int e = tid; e < WP_*16; e += 256) {
        int wp = e >> 4, i4 = (e & 15) * 4;
        short4 s4 = make_short4(0,0,0,0);
        if (interior && wp >= 1 && wp <= W_) {
            int w = wp - 1;
            s4.x = lb[(i4+0)*52 + w];
            s4.y = lb[(i4+1)*52 + w];
            s4.z = lb[(i4+2)*52 + w];
            s4.w = lb[(i4+3)*52 + w];
        }
        size_t pos = (size_t)t*PPLANE_ + hp*WP_ + wp;
        short* dst = xt + ((size_t)(b*2 + (i4 >> 5))*PPOS_ + pos)*32 + (i4 & 31);
        *(short4*)dst = s4;
    }
}

// ---------------- kernel 2: reduce FC + fc1 + sigmoid ----------------
__global__ __launch_bounds__(256) void fc_kernel(const float* __restrict__ gap,
        const float* __restrict__ w_reduce, const float* __restrict__ b_reduce,
        const float* __restrict__ w_fc1, const float* __restrict__ b_fc1,
        float* __restrict__ h_out) {
    __shared__ float gl[256];
    int t = threadIdx.x;
    {
        int b = t >> 4, j = t & 15;
        float a = b_reduce[j];
        #pragma unroll
        for (int c = 0; c < 64; ++c) a += gap[b*64 + c] * w_reduce[j*64 + c];
        gl[b*16 + j] = a;
    }
    __syncthreads();
    for (int idx = t; idx < 2048; idx += 256) {
        int b = idx >> 7, j = idx & 127;
        float v = b_fc1[j];
        #pragma unroll
        for (int i = 0; i < 16; ++i) v += gl[b*16 + i] * w_fc1[j*16 + i];
        h_out[idx] = 1.0f / (1.0f + expf(-v));
    }
}

// ---------------- kernel 3: dynamic weights bf16 (+ zero block) ----------------
__global__ __launch_bounds__(256) void wdyn_kernel(const float* __restrict__ w_fc2,
        const float* __restrict__ h, short* __restrict__ wdyn, short* __restrict__ zblk) {
    if (blockIdx.x == 0 && threadIdx.x < 128) zblk[threadIdx.x] = 0;
    int b = blockIdx.x / 27, tap = blockIdx.x % 27;
    short* dst = wdyn + ((size_t)b*27 + tap) * 4096;
    for (int e = threadIdx.x; e < 4096; e += 256) {
        int oc = e >> 6, ic = e & 63;
        float wv = w_fc2[(oc*64 + ic)*27 + tap];
        float hv = h[b*128 + 2*oc + (ic >> 5)];
        dst[e] = f2bf(wv * hv);
    }
}

#define DO_STEP(tap, r0, r1, r2, r3) do {                              \
    int _kd = (tap)/9, _rr = (tap)-_kd*9, _kh = _rr/3, _kw = _rr-_kh*3;\
    int _sb = (tzw + _kd)*180 + (hw4 + _kh)*18 + _kw + ln;             \
    __builtin_amdgcn_s_setprio(1);                                     \
    _Pragma("unroll")                                                  \
    for (int _j = 0; _j < 4; ++_j) {                                   \
        int _s = _sb + _j*18;                                          \
        bf16x8 _bv = *(const bf16x8*)&xs[_s*32 + ((kg ^ SWZ(_s)) * 8)];\
        acc[0][_j] = __builtin_amdgcn_mfma_f32_16x16x32_bf16(r0, _bv, acc[0][_j], 0, 0, 0); \
        acc[1][_j] = __builtin_amdgcn_mfma_f32_16x16x32_bf16(r1, _bv, acc[1][_j], 0, 0, 0); \
        acc[2][_j] = __builtin_amdgcn_mfma_f32_16x16x32_bf16(r2, _bv, acc[2][_j], 0, 0, 0); \
        acc[3][_j] = __builtin_amdgcn_mfma_f32_16x16x32_bf16(r3, _bv, acc[3][_j], 0, 0, 0); \
    }                                                                  \
    __builtin_amdgcn_s_setprio(0);                                     \
} while (0)

// ---------------- kernel 4: implicit-GEMM dynamic conv3d ----------------
// R10's proven 2-barrier structure at 3 blocks/CU (50,176B LDS, VGPR 72).
// Single change vs R10: the next-step weight prefetch is issued AFTER the
// second barrier, so barrier B drains nothing (vmcnt==0, free) and the load
// has the whole MFMA phase of cover before barrier A of step g+1 drains it.
__global__ __launch_bounds__(256, 3) void conv_kernel(const short* __restrict__ xt,
        const short* __restrict__ wdyn, const short* __restrict__ zblk,
        float* __restrict__ out) {
    __shared__ short xs[NS2*32];     // 46,080 B
    __shared__ short wb[2048];       //  4,096 B (one tap, one K-half)

    // XCD swizzle: 5760 blocks = 8 XCDs x 720 contiguous (5760 % 8 == 0)
    int bid = (blockIdx.x & 7) * 720 + (blockIdx.x >> 3);
    int b = bid / 360; int r = bid - b*360;
    int tzt = r / 24; r -= tzt*24;
    int tyt = r / 3;  int txt = r - tyt*3;
    int t0 = tzt*2, h0 = tyt*8, w0 = txt*16;

    int tid = threadIdx.x, wid = tid >> 6, lane = tid & 63;
    int ln = lane & 15, kg = lane >> 4;
    int l4 = lane >> 2, c = lane & 3;
    int tzw = wid & 1, hw4 = (wid >> 1) * 4;
    int woc = tid >> 2, wseg = tid & 3;          // weight staging role

    const short* wdb = wdyn + (size_t)b * 27 * 4096;

    f32x4 acc[4][4];
    #pragma unroll
    for (int mt = 0; mt < 4; ++mt)
        #pragma unroll
        for (int j = 0; j < 4; ++j) acc[mt][j] = f32x4{0.f, 0.f, 0.f, 0.f};

    auto stage_x = [&](int half) {               // 45 gload_lds over 4 waves
        const short* xbh = xt + (size_t)(b*2 + half) * PPOS_ * 32;
        #pragma unroll
        for (int ii = 0; ii < 12; ++ii) {
            int inst = ii*4 + wid;
            if (inst < 45) {
                int s = inst*16 + l4;
                int z = s / 180; int rr = s - z*180;
                int y = rr / 18; int xx = rr - y*18;
                int t = t0 + z - 1;
                int seg = (c ^ SWZ(s)) * 8;
                const short* src = ((unsigned)t < (unsigned)T_)
                    ? xbh + ((size_t)t*PPLANE_ + (h0+y)*WP_ + (w0+xx))*32 + seg
                    : zblk + seg;
                gload_lds16(src, xs + inst*512);
            }
        }
    };

    // prologue: stage xs half 0, prefetch tap-0 weights into a register
    stage_x(0);
    uint4 wr = *(const uint4*)(wdb + woc*64 + wseg*8);
    short* wdst = wb + woc*32 + ((wseg ^ SWZ(woc)) * 8);

    for (int g = 0; g < 54; ++g) {
        __syncthreads();                         // (A) wb reads of step g-1 done;
                                                 //     drains wr(g) — covered by
                                                 //     step g-1's MFMA phase
        *(uint4*)wdst = wr;                      // publish tap g weights
        __syncthreads();                         // (B) wb visible; vmcnt==0 -> free
        if (g < 53) {                            // prefetch tap g+1 (issued inside
            int gn = g + 1;                      //  the MFMA phase for max cover)
            int nt = gn - ((gn >= 27) ? 27 : 0);
            int nh = (gn >= 27) ? 32 : 0;
            wr = *(const uint4*)(wdb + nt*4096 + nh + woc*64 + wseg*8);
        }
        bf16x8 a0, a1, a2, a3;
        {
            int cw = (kg ^ SWZ(ln)) * 8;
            a0 = *(const bf16x8*)&wb[(ln     )*32 + cw];
            a1 = *(const bf16x8*)&wb[(ln + 16)*32 + cw];
            a2 = *(const bf16x8*)&wb[(ln + 32)*32 + cw];
            a3 = *(const bf16x8*)&wb[(ln + 48)*32 + cw];
        }
        int tap = g - ((g >= 27) ? 27 : 0);
        DO_STEP(tap, a0, a1, a2, a3);
        if (g == 26) {                           // half transition
            __syncthreads();                     // xs(0) reads complete
            stage_x(1);                          // drained by next sync (A)
        }
    }

    // epilogue: D layout col=lane&15 (pos=w), row=(lane>>4)*4+ri (oc)
    int t = t0 + tzw;
    int wv = w0 + ln;
    if (wv < W_) {
        #pragma unroll
        for (int mt = 0; mt < 4; ++mt) {
            size_t obase = ((size_t)(b*64 + mt*16 + kg*4) * T_ + t) * HW_;
            #pragma unroll
            for (int j = 0; j < 4; ++j) {
                float* o = out + obase + (h0 + hw4 + j)*W_ + wv;
                #pragma unroll
                for (int ri = 0; ri < 4; ++ri)
                    o[(size_t)ri * THW_] = acc[mt][j][ri];
            }
        }
    }
}

extern "C" void kernel_launch(void* const* d_in, const int* in_sizes, int n_in,
                              void* d_out, int out_size, void* d_ws, size_t ws_size,
                              hipStream_t stream) {
    const float* x        = (const float*)d_in[0];
    const float* w_reduce = (const float*)d_in[1];
    const float* b_reduce = (const float*)d_in[2];
    const float* w_fc1    = (const float*)d_in[3];
    const float* b_fc1    = (const float*)d_in[4];
    const float* w_fc2    = (const float*)d_in[5];
    float* out = (float*)d_out;

    // ws layout: gap 4KB | h 8KB | wdyn 3.375MB | zblk 256B | xt 186.5MB (+slack)
    float* gap  = (float*)d_ws;
    float* h    = gap + 1024;
    short* wdyn = (short*)(h + 2048);
    short* zblk = wdyn + (size_t)B_*27*4096;
    short* xt   = zblk + 128;

    hipMemsetAsync(gap, 0, 1024*sizeof(float), stream);   // atomic accumulator
    transpose_kernel<<<B_*T_*HP_, 256, 0, stream>>>(x, xt, gap);
    fc_kernel       <<<1,         256, 0, stream>>>(gap, w_reduce, b_reduce, w_fc1, b_fc1, h);
    wdyn_kernel     <<<B_*27,     256, 0, stream>>>(w_fc2, h, wdyn, zblk);
    conv_kernel     <<<B_*360,    256, 0, stream>>>(xt, wdyn, zblk, out);
}